// Round 1
// baseline (1877.251 us; speedup 1.0000x reference)
//
#include <hip/hip_runtime.h>
#include <hip/hip_bf16.h>
#include <math.h>

#define B_ 4
#define C_ 256
#define N_ 2048
#define H_ 8
#define D_ 64
#define BH_ (B_*H_)
#define BN_EPS 1e-5f

#define TM 64
#define TN 64
#define KB 16
#define LPAD 68   // TM+4 padded LDS leading dim (keeps float4 rows 16B-aligned: 68*4=272=16*17)

struct GP {
  const float *x, *w_qk, *w_v, *b_v, *w_t, *b_t, *bn_g, *bn_b, *bn_m, *bn_v;
  const float *w_lin, *lbn_g, *lbn_b, *lbn_m, *lbn_v;
  float *P, *HO, *Abuf, *Vbuf, *Rbuf, *cs, *rm, *rs;
  float *out;
  int cs0;
};

// EPI: 0 = P = w_qk*x            (M=64,  K=256)
//      1 = V = w_v*x + b_v       (M=256, K=256)
//      2 = R = (V*A) / colsum    (M=256, K=2048)
//      3 = HO = headout(w_t*(x-R)) (M=256, K=256)
//      4 = out = leaky(bn(w_lin*HO)) (M=256, K=2048), z = batch
template<int EPI>
__global__ __launch_bounds__(256) void gemm_k(GP p) {
  const int t  = threadIdx.x;
  const int tx = t & 15, ty = t >> 4;
  const int n0 = blockIdx.x * TN;
  const int m0 = blockIdx.y * TM;
  const int z  = blockIdx.z;

  constexpr int K = (EPI == 2 || EPI == 4) ? 2048 : 256;

  int bh = p.cs0 + z, b = bh / H_, h = bh % H_, zi = z;
  const float *A, *Bm, *B2 = nullptr;
  float *Cw;
  int lda;
  if constexpr (EPI == 0) {
    A = p.w_qk + (size_t)h * D_ * C_; lda = C_;
    Bm = p.x + (size_t)b * C_ * N_;
    Cw = p.P + (size_t)bh * D_ * N_;
  } else if constexpr (EPI == 1) {
    A = p.w_v + (size_t)h * C_ * C_; lda = C_;
    Bm = p.x + (size_t)b * C_ * N_;
    Cw = p.Vbuf + (size_t)zi * C_ * N_;
  } else if constexpr (EPI == 2) {
    A = p.Vbuf + (size_t)zi * C_ * N_; lda = N_;
    Bm = p.Abuf + (size_t)zi * N_ * N_;
    Cw = p.Rbuf + (size_t)zi * C_ * N_;
  } else if constexpr (EPI == 3) {
    A = p.w_t + (size_t)h * C_ * C_; lda = C_;
    Bm = p.x + (size_t)b * C_ * N_;
    B2 = p.Rbuf + (size_t)zi * C_ * N_;
    Cw = p.HO + (size_t)bh * C_ * N_;
  } else { // EPI == 4, z = batch index
    A = p.w_lin; lda = H_ * C_;
    Bm = p.HO + (size_t)z * H_ * C_ * N_;
    Cw = p.out + (size_t)z * C_ * N_;
    b = z;
  }

  __shared__ float As[KB][LPAD];
  __shared__ float Bs[KB][LPAD];

  const int am = t >> 2;         // 0..63 (row of A tile)
  const int ak = (t & 3) * 4;    // 0,4,8,12
  const int bk = t >> 4;         // 0..15 (row of B tile)
  const int bn = (t & 15) * 4;   // 0..60

  float acc[4][4] = {};

  for (int k0 = 0; k0 < K; k0 += KB) {
    float4 av = *(const float4*)(A + (size_t)(m0 + am) * lda + k0 + ak);
    float4 bv = *(const float4*)(Bm + (size_t)(k0 + bk) * N_ + n0 + bn);
    if constexpr (EPI == 3) {
      float4 rv = *(const float4*)(B2 + (size_t)(k0 + bk) * N_ + n0 + bn);
      bv.x -= rv.x; bv.y -= rv.y; bv.z -= rv.z; bv.w -= rv.w;
    }
    __syncthreads();
    As[ak + 0][am] = av.x; As[ak + 1][am] = av.y;
    As[ak + 2][am] = av.z; As[ak + 3][am] = av.w;
    *(float4*)&Bs[bk][bn] = bv;
    __syncthreads();
#pragma unroll
    for (int kk = 0; kk < KB; ++kk) {
      float4 a4 = *(const float4*)&As[kk][ty * 4];
      float4 b4 = *(const float4*)&Bs[kk][tx * 4];
      float aa[4] = {a4.x, a4.y, a4.z, a4.w};
      float bb[4] = {b4.x, b4.y, b4.z, b4.w};
#pragma unroll
      for (int i = 0; i < 4; ++i)
#pragma unroll
        for (int j = 0; j < 4; ++j)
          acc[i][j] = fmaf(aa[i], bb[j], acc[i][j]);
    }
  }

  const int col0 = n0 + tx * 4;
  if constexpr (EPI == 0) {
#pragma unroll
    for (int i = 0; i < 4; ++i) {
      int r = m0 + ty * 4 + i;
      *(float4*)(Cw + (size_t)r * N_ + col0) =
          make_float4(acc[i][0], acc[i][1], acc[i][2], acc[i][3]);
    }
  } else if constexpr (EPI == 1) {
#pragma unroll
    for (int i = 0; i < 4; ++i) {
      int r = m0 + ty * 4 + i;
      float bs = p.b_v[h * C_ + r];
      *(float4*)(Cw + (size_t)r * N_ + col0) =
          make_float4(acc[i][0] + bs, acc[i][1] + bs, acc[i][2] + bs, acc[i][3] + bs);
    }
  } else if constexpr (EPI == 2) {
    float inv[4];
#pragma unroll
    for (int j = 0; j < 4; ++j)
      inv[j] = 1.0f / (1e-9f + p.cs[(size_t)zi * N_ + col0 + j]);
#pragma unroll
    for (int i = 0; i < 4; ++i) {
      int r = m0 + ty * 4 + i;
      *(float4*)(Cw + (size_t)r * N_ + col0) =
          make_float4(acc[i][0] * inv[0], acc[i][1] * inv[1],
                      acc[i][2] * inv[2], acc[i][3] * inv[3]);
    }
  } else if constexpr (EPI == 3) {
    const float* xb = p.x + (size_t)b * C_ * N_;
#pragma unroll
    for (int i = 0; i < 4; ++i) {
      int r = m0 + ty * 4 + i;
      int hc = h * C_ + r;
      float bt = p.b_t[hc], mm = p.bn_m[hc], bb2 = p.bn_b[hc];
      float sc = p.bn_g[hc] / sqrtf(p.bn_v[hc] + BN_EPS);
      float4 xv = *(const float4*)(xb + (size_t)r * N_ + col0);
      float4 v;
      v.x = xv.x + fmaxf((acc[i][0] + bt - mm) * sc + bb2, 0.f);
      v.y = xv.y + fmaxf((acc[i][1] + bt - mm) * sc + bb2, 0.f);
      v.z = xv.z + fmaxf((acc[i][2] + bt - mm) * sc + bb2, 0.f);
      v.w = xv.w + fmaxf((acc[i][3] + bt - mm) * sc + bb2, 0.f);
      *(float4*)(Cw + (size_t)r * N_ + col0) = v;
    }
  } else { // EPI == 4
#pragma unroll
    for (int i = 0; i < 4; ++i) {
      int r = m0 + ty * 4 + i;
      float mm = p.lbn_m[r], bb2 = p.lbn_b[r];
      float sc = p.lbn_g[r] / sqrtf(p.lbn_v[r] + BN_EPS);
      float4 v;
      float y0 = (acc[i][0] - mm) * sc + bb2;
      float y1 = (acc[i][1] - mm) * sc + bb2;
      float y2 = (acc[i][2] - mm) * sc + bb2;
      float y3 = (acc[i][3] - mm) * sc + bb2;
      v.x = y0 >= 0.f ? y0 : 0.2f * y0;
      v.y = y1 >= 0.f ? y1 : 0.2f * y1;
      v.z = y2 >= 0.f ? y2 : 0.2f * y2;
      v.w = y3 >= 0.f ? y3 : 0.2f * y3;
      *(float4*)(Cw + (size_t)r * N_ + col0) = v;
    }
  }
}

// E = P^T P, symmetric: compute upper-triangle tiles, mirror-write lower.
__global__ __launch_bounds__(256) void energy_k(const float* __restrict__ Pall,
                                                float* __restrict__ Ebuf, int cs0) {
  const int z = blockIdx.z;
  const int bh = cs0 + z;
  const int nt = blockIdx.y, mt = blockIdx.x;
  if (mt < nt) return;
  const float* Pp = Pall + (size_t)bh * D_ * N_;
  float* E = Ebuf + (size_t)z * N_ * N_;
  __shared__ float Pn[D_][LPAD];
  __shared__ float Pm[D_][LPAD];
  const int t = threadIdx.x;
  const int n0 = nt * 64, m0 = mt * 64;
#pragma unroll
  for (int i = 0; i < 4; ++i) {
    int idx = i * 256 + t;
    int d = idx >> 4, q = (idx & 15) * 4;
    *(float4*)&Pn[d][q] = *(const float4*)(Pp + (size_t)d * N_ + n0 + q);
    *(float4*)&Pm[d][q] = *(const float4*)(Pp + (size_t)d * N_ + m0 + q);
  }
  __syncthreads();
  const int tx = t & 15, ty = t >> 4;
  float acc[4][4] = {};
#pragma unroll 8
  for (int d = 0; d < D_; ++d) {
    float4 a4 = *(const float4*)&Pn[d][ty * 4];
    float4 b4 = *(const float4*)&Pm[d][tx * 4];
    float aa[4] = {a4.x, a4.y, a4.z, a4.w};
    float bb[4] = {b4.x, b4.y, b4.z, b4.w};
#pragma unroll
    for (int i = 0; i < 4; ++i)
#pragma unroll
      for (int j = 0; j < 4; ++j)
        acc[i][j] = fmaf(aa[i], bb[j], acc[i][j]);
  }
#pragma unroll
  for (int i = 0; i < 4; ++i) {
    int r = n0 + ty * 4 + i;
    *(float4*)(E + (size_t)r * N_ + m0 + tx * 4) =
        make_float4(acc[i][0], acc[i][1], acc[i][2], acc[i][3]);
  }
  if (mt > nt) {
    __syncthreads();  // done reading Pn; reuse as transpose staging
#pragma unroll
    for (int i = 0; i < 4; ++i)
#pragma unroll
      for (int j = 0; j < 4; ++j)
        Pn[tx * 4 + j][ty * 4 + i] = acc[i][j];
    __syncthreads();
#pragma unroll
    for (int i = 0; i < 4; ++i) {
      int idx = i * 256 + t;
      int rr = idx >> 4, q = (idx & 15) * 4;
      *(float4*)(E + (size_t)(m0 + rr) * N_ + n0 + q) = *(float4*)&Pn[rr][q];
    }
  }
}

// pass1: per-row max and RECIPROCAL of sum(exp(row - max))
__global__ __launch_bounds__(256) void sm_pass1(const float* __restrict__ Ebuf,
                                                float* __restrict__ rm,
                                                float* __restrict__ rs) {
  const int z = blockIdx.y, row = blockIdx.x;
  const float* Er = Ebuf + (size_t)z * N_ * N_ + (size_t)row * N_;
  const int t = threadIdx.x;
  float4 v0 = *(const float4*)(Er + t * 4);
  float4 v1 = *(const float4*)(Er + 1024 + t * 4);
  float mx = fmaxf(fmaxf(fmaxf(v0.x, v0.y), fmaxf(v0.z, v0.w)),
                   fmaxf(fmaxf(v1.x, v1.y), fmaxf(v1.z, v1.w)));
  __shared__ float sb[8], sb2[8];
  for (int o = 32; o; o >>= 1) mx = fmaxf(mx, __shfl_xor(mx, o, 64));
  int lane = t & 63, w = t >> 6;
  if (!lane) sb[w] = mx;
  __syncthreads();
  mx = fmaxf(fmaxf(sb[0], sb[1]), fmaxf(sb[2], sb[3]));
  float s = __expf(v0.x - mx) + __expf(v0.y - mx) + __expf(v0.z - mx) + __expf(v0.w - mx) +
            __expf(v1.x - mx) + __expf(v1.y - mx) + __expf(v1.z - mx) + __expf(v1.w - mx);
  for (int o = 32; o; o >>= 1) s += __shfl_xor(s, o, 64);
  if (!lane) sb2[w] = s;
  __syncthreads();
  if (t == 0) {
    rm[(size_t)z * N_ + row] = mx;
    rs[(size_t)z * N_ + row] = 1.0f / (sb2[0] + sb2[1] + sb2[2] + sb2[3]);
  }
}

// pass2: A[m][n] = exp(E-rm[m])*rs[m]  (in place), and via exact symmetry of E:
// colsum[m] = sum_n exp(E[m][n]-rm[n])*rs[n]
__global__ __launch_bounds__(256) void sm_pass2(float* __restrict__ Ebuf,
                                                const float* __restrict__ rm,
                                                const float* __restrict__ rs,
                                                float* __restrict__ cs) {
  const int z = blockIdx.y, m = blockIdx.x;
  float* Er = Ebuf + (size_t)z * N_ * N_ + (size_t)m * N_;
  const float* rmz = rm + (size_t)z * N_;
  const float* rsz = rs + (size_t)z * N_;
  const int t = threadIdx.x;
  const float mrow = rmz[m];
  const float invr = rsz[m];
  float csum = 0.f;
#pragma unroll
  for (int half = 0; half < 2; ++half) {
    int n = half * 1024 + t * 4;
    float4 e = *(const float4*)(Er + n);
    float4 m4 = *(const float4*)(rmz + n);
    float4 s4 = *(const float4*)(rsz + n);
    float4 a;
    a.x = __expf(e.x - mrow) * invr;
    a.y = __expf(e.y - mrow) * invr;
    a.z = __expf(e.z - mrow) * invr;
    a.w = __expf(e.w - mrow) * invr;
    csum += __expf(e.x - m4.x) * s4.x + __expf(e.y - m4.y) * s4.y +
            __expf(e.z - m4.z) * s4.z + __expf(e.w - m4.w) * s4.w;
    *(float4*)(Er + n) = a;
  }
  __shared__ float sb[8];
  for (int o = 32; o; o >>= 1) csum += __shfl_xor(csum, o, 64);
  int lane = t & 63, w = t >> 6;
  if (!lane) sb[w] = csum;
  __syncthreads();
  if (t == 0) cs[(size_t)z * N_ + m] = sb[0] + sb[1] + sb[2] + sb[3];
}

static inline int imin(int a, int b) { return a < b ? a : b; }

extern "C" void kernel_launch(void* const* d_in, const int* in_sizes, int n_in,
                              void* d_out, int out_size, void* d_ws, size_t ws_size,
                              hipStream_t stream) {
  GP p;
  p.x     = (const float*)d_in[0];
  p.w_qk  = (const float*)d_in[1];
  p.w_v   = (const float*)d_in[2];
  p.b_v   = (const float*)d_in[3];
  p.w_t   = (const float*)d_in[4];
  p.b_t   = (const float*)d_in[5];
  p.bn_g  = (const float*)d_in[6];
  p.bn_b  = (const float*)d_in[7];
  p.bn_m  = (const float*)d_in[8];
  p.bn_v  = (const float*)d_in[9];
  p.w_lin = (const float*)d_in[10];
  p.lbn_g = (const float*)d_in[11];
  p.lbn_b = (const float*)d_in[12];
  p.lbn_m = (const float*)d_in[13];
  p.lbn_v = (const float*)d_in[14];
  p.out   = (float*)d_out;

  float* w = (float*)d_ws;
  size_t off = 0;
  p.P  = w + off; off += (size_t)BH_ * D_ * N_;   // 16 MB
  p.HO = w + off; off += (size_t)BH_ * C_ * N_;   // 64 MB
  const size_t fixedf = off;
  const size_t perbh = (size_t)N_ * N_ + 2 * (size_t)C_ * N_ + 3 * (size_t)N_;
  size_t availf = (ws_size / 4 > fixedf) ? (ws_size / 4 - fixedf) : 0;
  int chunk = (int)(availf / perbh);
  if (chunk < 1) chunk = 1;
  if (chunk > BH_) chunk = BH_;

  p.Abuf = w + fixedf;
  p.Vbuf = p.Abuf + (size_t)chunk * N_ * N_;
  p.Rbuf = p.Vbuf + (size_t)chunk * C_ * N_;
  p.cs   = p.Rbuf + (size_t)chunk * C_ * N_;
  p.rm   = p.cs + (size_t)chunk * N_;
  p.rs   = p.rm + (size_t)chunk * N_;

  dim3 blk(256);

  p.cs0 = 0;
  gemm_k<0><<<dim3(N_ / TN, 1, BH_), blk, 0, stream>>>(p);

  for (int c0 = 0; c0 < BH_; c0 += chunk) {
    int cur = imin(chunk, BH_ - c0);
    p.cs0 = c0;
    gemm_k<1><<<dim3(N_ / TN, C_ / TM, cur), blk, 0, stream>>>(p);
    energy_k<<<dim3(N_ / 64, N_ / 64, cur), blk, 0, stream>>>(p.P, p.Abuf, c0);
    sm_pass1<<<dim3(N_, cur), blk, 0, stream>>>(p.Abuf, p.rm, p.rs);
    sm_pass2<<<dim3(N_, cur), blk, 0, stream>>>(p.Abuf, p.rm, p.rs, p.cs);
    gemm_k<2><<<dim3(N_ / TN, C_ / TM, cur), blk, 0, stream>>>(p);
    gemm_k<3><<<dim3(N_ / TN, C_ / TM, cur), blk, 0, stream>>>(p);
  }

  p.cs0 = 0;
  gemm_k<4><<<dim3(N_ / TN, C_ / TM, B_), blk, 0, stream>>>(p);
}

// Round 2
// 751.414 us; speedup vs baseline: 2.4983x; 2.4983x over previous
//
#include <hip/hip_runtime.h>
#include <math.h>

#define B_ 4
#define C_ 256
#define N_ 2048
#define H_ 8
#define D_ 64
#define BH_ 32
#define HC_ 2048
#define BN_EPS 1e-5f

typedef __attribute__((ext_vector_type(8))) short s8v;
typedef __attribute__((ext_vector_type(4))) short s4v;
typedef __attribute__((ext_vector_type(4))) float f32x4;

#define MFMA __builtin_amdgcn_mfma_f32_16x16x32_bf16

static __device__ __forceinline__ unsigned short f2b(float f) {
  union { float f; unsigned int i; } v; v.f = f;
  unsigned int r = v.i + 0x7FFFu + ((v.i >> 16) & 1u);
  return (unsigned short)(r >> 16);
}
static __device__ __forceinline__ float b2f(unsigned short u) {
  union { unsigned int i; float f; } v; v.i = ((unsigned int)u) << 16;
  return v.f;
}

struct GP {
  const float *x, *w_qk, *w_v, *b_v, *w_t, *b_t, *bn_g, *bn_b, *bn_m, *bn_v;
  const float *w_lin, *lbn_g, *lbn_b, *lbn_m, *lbn_v;
  short *PThi, *PTlo, *xTb, *HOT, *wvb, *wtb, *wlinb, *Vb, *ATT, *xmr;
  float *E, *cs, *rm, *rs, *out;
  int cs0;
};

// fp32 -> bf16 elementwise convert (n = 524288 exactly for all three weights)
__global__ __launch_bounds__(256) void cvt_k(const float* __restrict__ in,
                                             short* __restrict__ out) {
  int i = (blockIdx.x * 256 + threadIdx.x) * 4;
  float4 v = *(const float4*)(in + i);
  s4v o = { (short)f2b(v.x), (short)f2b(v.y), (short)f2b(v.z), (short)f2b(v.w) };
  *(s4v*)(out + i) = o;
}

// x [B][C][N] fp32 -> xTb [B][N][C] bf16
__global__ __launch_bounds__(256) void xT_k(const float* __restrict__ x,
                                            short* __restrict__ xTb) {
  const int n0 = blockIdx.x * 64, c0 = blockIdx.y * 64, b = blockIdx.z;
  const float* xb = x + (size_t)b * C_ * N_;
  __shared__ float sm[64][65];
  const int t = threadIdx.x;
#pragma unroll
  for (int i = 0; i < 4; ++i) {
    int idx = i * 256 + t;
    int c = idx >> 4, j = (idx & 15) * 4;
    float4 v = *(const float4*)(xb + (size_t)(c0 + c) * N_ + n0 + j);
    sm[j + 0][c] = v.x; sm[j + 1][c] = v.y; sm[j + 2][c] = v.z; sm[j + 3][c] = v.w;
  }
  __syncthreads();
  short* xz = xTb + (size_t)b * N_ * C_;
#pragma unroll
  for (int i = 0; i < 2; ++i) {
    int idx = i * 256 + t;
    int n = idx >> 3, cg = (idx & 7) * 8;
    s8v o;
#pragma unroll
    for (int d = 0; d < 8; ++d) o[d] = (short)f2b(sm[n][cg + d]);
    *(s8v*)(xz + (size_t)(n0 + n) * C_ + c0 + cg) = o;
  }
}

// P = w_qk * x, fp32; writes PT_hi / PT_lo [bh][N][D] bf16 (transposed, hi/lo split)
__global__ __launch_bounds__(256) void p_k(GP p) {
  const int t = threadIdx.x;
  const int tx = t & 15, ty = t >> 4;
  const int n0 = blockIdx.x * 64;
  const int bh = blockIdx.z;
  const int b = bh / H_, h = bh % H_;
  const float* A = p.w_qk + (size_t)h * D_ * C_;
  const float* Bm = p.x + (size_t)b * C_ * N_;
  __shared__ float As[16][68];
  __shared__ float Bs[16][68];
  __shared__ float sm[64][65];
  const int am = t >> 2, ak = (t & 3) * 4;
  const int bk = t >> 4, bn = (t & 15) * 4;
  float acc[4][4] = {};
  for (int k0 = 0; k0 < C_; k0 += 16) {
    float4 av = *(const float4*)(A + (size_t)am * C_ + k0 + ak);
    float4 bv = *(const float4*)(Bm + (size_t)(k0 + bk) * N_ + n0 + bn);
    __syncthreads();
    As[ak + 0][am] = av.x; As[ak + 1][am] = av.y;
    As[ak + 2][am] = av.z; As[ak + 3][am] = av.w;
    *(float4*)&Bs[bk][bn] = bv;
    __syncthreads();
#pragma unroll
    for (int kk = 0; kk < 16; ++kk) {
      float4 a4 = *(const float4*)&As[kk][ty * 4];
      float4 b4 = *(const float4*)&Bs[kk][tx * 4];
      float aa[4] = {a4.x, a4.y, a4.z, a4.w};
      float bb[4] = {b4.x, b4.y, b4.z, b4.w};
#pragma unroll
      for (int i = 0; i < 4; ++i)
#pragma unroll
        for (int j = 0; j < 4; ++j)
          acc[i][j] = fmaf(aa[i], bb[j], acc[i][j]);
    }
  }
  // acc[i][j] = P[d = ty*4+i][n_local = tx*4+j]; transpose via LDS
#pragma unroll
  for (int i = 0; i < 4; ++i)
#pragma unroll
    for (int j = 0; j < 4; ++j)
      sm[tx * 4 + j][ty * 4 + i] = acc[i][j];
  __syncthreads();
  short* PHz = p.PThi + (size_t)bh * N_ * D_;
  short* PLz = p.PTlo + (size_t)bh * N_ * D_;
  const int nl = t >> 2, dg = (t & 3) * 16;
  s8v h8[2], l8[2];
#pragma unroll
  for (int g = 0; g < 2; ++g)
#pragma unroll
    for (int d = 0; d < 8; ++d) {
      float v = sm[nl][dg + g * 8 + d];
      unsigned short hu = f2b(v);
      h8[g][d] = (short)hu;
      l8[g][d] = (short)f2b(v - b2f(hu));
    }
#pragma unroll
  for (int g = 0; g < 2; ++g) {
    *(s8v*)(PHz + (size_t)(n0 + nl) * D_ + dg + g * 8) = h8[g];
    *(s8v*)(PLz + (size_t)(n0 + nl) * D_ + dg + g * 8) = l8[g];
  }
}

// E = (Phi+Plo)^T (Phi+Plo) dropping lo*lo; full square, fp32 out. K=64.
__global__ __launch_bounds__(256) void eng_k(GP p) {
  const int t = threadIdx.x;
  const int wave = t >> 6, lane = t & 63;
  const int wr = wave >> 1, wc = wave & 1;
  const int l15 = lane & 15, l4 = lane >> 4;
  const int c0 = blockIdx.x * 128;
  const int r0 = blockIdx.y * 128;
  const int z = blockIdx.z;
  const int bh = p.cs0 + z;
  const short* Phi = p.PThi + (size_t)bh * N_ * D_;
  const short* Plo = p.PTlo + (size_t)bh * N_ * D_;

  __shared__ short Rh[128 * 64], Rl[128 * 64], Ch[128 * 64], Cl[128 * 64];

#pragma unroll
  for (int i = 0; i < 4; ++i) {
    int idx = i * 256 + t;
    int row = idx >> 3, kg = (idx & 7) * 8;
    *(s8v*)&Rh[row * 64 + kg] = *(const s8v*)(Phi + (size_t)(r0 + row) * D_ + kg);
    *(s8v*)&Rl[row * 64 + kg] = *(const s8v*)(Plo + (size_t)(r0 + row) * D_ + kg);
    *(s8v*)&Ch[row * 64 + kg] = *(const s8v*)(Phi + (size_t)(c0 + row) * D_ + kg);
    *(s8v*)&Cl[row * 64 + kg] = *(const s8v*)(Plo + (size_t)(c0 + row) * D_ + kg);
  }
  __syncthreads();
  f32x4 acc[4][4] = {};
#pragma unroll
  for (int s = 0; s < 2; ++s) {
    s8v ah[4], al[4], bh4[4], bl[4];
#pragma unroll
    for (int m = 0; m < 4; ++m) {
      int row = wr * 64 + m * 16 + l15;
      ah[m] = *(const s8v*)&Rh[row * 64 + s * 32 + l4 * 8];
      al[m] = *(const s8v*)&Rl[row * 64 + s * 32 + l4 * 8];
    }
#pragma unroll
    for (int n = 0; n < 4; ++n) {
      int row = wc * 64 + n * 16 + l15;
      bh4[n] = *(const s8v*)&Ch[row * 64 + s * 32 + l4 * 8];
      bl[n] = *(const s8v*)&Cl[row * 64 + s * 32 + l4 * 8];
    }
#pragma unroll
    for (int m = 0; m < 4; ++m)
#pragma unroll
      for (int n = 0; n < 4; ++n) {
        acc[m][n] = MFMA(ah[m], bh4[n], acc[m][n], 0, 0, 0);
        acc[m][n] = MFMA(ah[m], bl[n], acc[m][n], 0, 0, 0);
        acc[m][n] = MFMA(al[m], bh4[n], acc[m][n], 0, 0, 0);
      }
  }
  float* Ez = p.E + (size_t)z * N_ * N_;
#pragma unroll
  for (int m = 0; m < 4; ++m)
#pragma unroll
    for (int r = 0; r < 4; ++r) {
      int row = r0 + wr * 64 + m * 16 + l4 * 4 + r;
#pragma unroll
      for (int n = 0; n < 4; ++n)
        Ez[(size_t)row * N_ + c0 + wc * 64 + n * 16 + l15] = acc[m][n][r];
    }
}

// pass1: per-row max and reciprocal of sum(exp(row-max)) over E rows
__global__ __launch_bounds__(256) void sm_pass1(const float* __restrict__ Ebuf,
                                                float* __restrict__ rm,
                                                float* __restrict__ rs) {
  const int z = blockIdx.y, row = blockIdx.x;
  const float* Er = Ebuf + (size_t)z * N_ * N_ + (size_t)row * N_;
  const int t = threadIdx.x;
  float4 v0 = *(const float4*)(Er + t * 4);
  float4 v1 = *(const float4*)(Er + 1024 + t * 4);
  float mx = fmaxf(fmaxf(fmaxf(v0.x, v0.y), fmaxf(v0.z, v0.w)),
                   fmaxf(fmaxf(v1.x, v1.y), fmaxf(v1.z, v1.w)));
  __shared__ float sb[8], sb2[8];
  for (int o = 32; o; o >>= 1) mx = fmaxf(mx, __shfl_xor(mx, o, 64));
  int lane = t & 63, w = t >> 6;
  if (!lane) sb[w] = mx;
  __syncthreads();
  mx = fmaxf(fmaxf(sb[0], sb[1]), fmaxf(sb[2], sb[3]));
  float s = __expf(v0.x - mx) + __expf(v0.y - mx) + __expf(v0.z - mx) + __expf(v0.w - mx) +
            __expf(v1.x - mx) + __expf(v1.y - mx) + __expf(v1.z - mx) + __expf(v1.w - mx);
  for (int o = 32; o; o >>= 1) s += __shfl_xor(s, o, 64);
  if (!lane) sb2[w] = s;
  __syncthreads();
  if (t == 0) {
    rm[(size_t)z * N_ + row] = mx;
    rs[(size_t)z * N_ + row] = 1.0f / (sb2[0] + sb2[1] + sb2[2] + sb2[3]);
  }
}

// pass2: ATT[m][n] = attn^T = exp(E[m][n]-rm[n])*rs[n] (bf16), cs[m] = row sum
__global__ __launch_bounds__(256) void sm_pass2(GP p) {
  const int z = blockIdx.y, m = blockIdx.x;
  const float* Er = p.E + (size_t)z * N_ * N_ + (size_t)m * N_;
  short* Ar = p.ATT + (size_t)z * N_ * N_ + (size_t)m * N_;
  const float* rmz = p.rm + (size_t)z * N_;
  const float* rsz = p.rs + (size_t)z * N_;
  const int t = threadIdx.x;
  float csum = 0.f;
#pragma unroll
  for (int half = 0; half < 2; ++half) {
    int n = half * 1024 + t * 4;
    float4 e = *(const float4*)(Er + n);
    float4 m4 = *(const float4*)(rmz + n);
    float4 s4 = *(const float4*)(rsz + n);
    float a0 = __expf(e.x - m4.x) * s4.x;
    float a1 = __expf(e.y - m4.y) * s4.y;
    float a2 = __expf(e.z - m4.z) * s4.z;
    float a3 = __expf(e.w - m4.w) * s4.w;
    csum += a0 + a1 + a2 + a3;
    s4v o = { (short)f2b(a0), (short)f2b(a1), (short)f2b(a2), (short)f2b(a3) };
    *(s4v*)(Ar + n) = o;
  }
  __shared__ float sb[4];
  for (int o = 32; o; o >>= 1) csum += __shfl_xor(csum, o, 64);
  int lane = t & 63, w = t >> 6;
  if (!lane) sb[w] = csum;
  __syncthreads();
  if (t == 0) p.cs[(size_t)z * N_ + m] = sb[0] + sb[1] + sb[2] + sb[3];
}

// Unified bf16 MFMA GEMM, 128x128 tile, K-step 32.
// EPI 1: V = w_v*x + b_v          -> Vb bf16 [z][C][N]
// EPI 2: R0 = V*ATT^T; xmr = (x - R0/cs)^T bf16 [z][N][C]
// EPI 3: HO = x + relu(bn(w_t*xmr^T + b_t)) -> HOT bf16 [b][N][HC] (transposed)
// EPI 4: out = leaky(bn(w_lin*HOT^T))      fp32 [b][C][N]
template<int EPI>
__global__ __launch_bounds__(256) void mm_k(GP p) {
  constexpr int K = (EPI == 2 || EPI == 4) ? 2048 : 256;
  const int t = threadIdx.x;
  const int wave = t >> 6, lane = t & 63;
  const int wr = wave >> 1, wc = wave & 1;
  const int l15 = lane & 15, l4 = lane >> 4;
  const int n0 = blockIdx.x * 128;
  const int m0 = blockIdx.y * 128;
  const int z = blockIdx.z;
  int bh = p.cs0 + z, b = bh / H_, h = bh % H_;

  const short *Ag, *Bg;
  if constexpr (EPI == 1)      { Ag = p.wvb + h * C_ * C_; Bg = p.xTb + (size_t)b * N_ * C_; }
  else if constexpr (EPI == 2) { Ag = p.Vb + (size_t)z * C_ * N_; Bg = p.ATT + (size_t)z * N_ * N_; }
  else if constexpr (EPI == 3) { Ag = p.wtb + h * C_ * C_; Bg = p.xmr + (size_t)z * N_ * C_; }
  else                         { Ag = p.wlinb; Bg = p.HOT + (size_t)z * N_ * HC_; b = z; }

  __shared__ short As[128 * 32];
  __shared__ short Bs[128 * 32];

  f32x4 acc[4][4] = {};

  for (int k0 = 0; k0 < K; k0 += 32) {
    s8v va[2], vb[2];
#pragma unroll
    for (int i = 0; i < 2; ++i) {
      int idx = i * 256 + t;
      int row = idx >> 2, kg = (idx & 3) * 8;
      va[i] = *(const s8v*)(Ag + (size_t)(m0 + row) * K + k0 + kg);
      vb[i] = *(const s8v*)(Bg + (size_t)(n0 + row) * K + k0 + kg);
    }
    __syncthreads();
#pragma unroll
    for (int i = 0; i < 2; ++i) {
      int idx = i * 256 + t;
      int row = idx >> 2, kg = (idx & 3) * 8;
      *(s8v*)&As[row * 32 + kg] = va[i];
      *(s8v*)&Bs[row * 32 + kg] = vb[i];
    }
    __syncthreads();
    s8v af[4], bf[4];
#pragma unroll
    for (int m = 0; m < 4; ++m) af[m] = *(const s8v*)&As[(wr * 64 + m * 16 + l15) * 32 + l4 * 8];
#pragma unroll
    for (int n = 0; n < 4; ++n) bf[n] = *(const s8v*)&Bs[(wc * 64 + n * 16 + l15) * 32 + l4 * 8];
#pragma unroll
    for (int m = 0; m < 4; ++m)
#pragma unroll
      for (int n = 0; n < 4; ++n)
        acc[m][n] = MFMA(af[m], bf[n], acc[m][n], 0, 0, 0);
  }

  if constexpr (EPI == 1) {
    short* Vz = p.Vb + (size_t)z * C_ * N_;
#pragma unroll
    for (int m = 0; m < 4; ++m)
#pragma unroll
      for (int r = 0; r < 4; ++r) {
        int e = m0 + wr * 64 + m * 16 + l4 * 4 + r;
        float bias = p.b_v[h * C_ + e];
#pragma unroll
        for (int n = 0; n < 4; ++n) {
          int c = n0 + wc * 64 + n * 16 + l15;
          Vz[(size_t)e * N_ + c] = (short)f2b(acc[m][n][r] + bias);
        }
      }
  } else if constexpr (EPI == 2) {
    __shared__ short Tr[128 * 128];
    const float* xb = p.x + (size_t)b * C_ * N_;
    const float* csz = p.cs + (size_t)z * N_;
    float inv[4];
#pragma unroll
    for (int n = 0; n < 4; ++n)
      inv[n] = 1.0f / (1e-9f + csz[n0 + wc * 64 + n * 16 + l15]);
#pragma unroll
    for (int m = 0; m < 4; ++m)
#pragma unroll
      for (int r = 0; r < 4; ++r) {
        int e = m0 + wr * 64 + m * 16 + l4 * 4 + r;
        int el = e - m0;
#pragma unroll
        for (int n = 0; n < 4; ++n) {
          int cl = wc * 64 + n * 16 + l15;
          float val = xb[(size_t)e * N_ + n0 + cl] - acc[m][n][r] * inv[n];
          Tr[cl * 128 + el] = (short)f2b(val);
        }
      }
    __syncthreads();
    short* xz = p.xmr + (size_t)z * N_ * C_;
#pragma unroll
    for (int it = 0; it < 8; ++it) {
      int idx = it * 256 + t;
      int cl = idx >> 4, eg = (idx & 15) * 8;
      *(s8v*)(xz + (size_t)(n0 + cl) * C_ + m0 + eg) = *(const s8v*)&Tr[cl * 128 + eg];
    }
  } else if constexpr (EPI == 3) {
    __shared__ short Tr[128 * 128];
    const float* xb = p.x + (size_t)b * C_ * N_;
#pragma unroll
    for (int m = 0; m < 4; ++m)
#pragma unroll
      for (int r = 0; r < 4; ++r) {
        int e = m0 + wr * 64 + m * 16 + l4 * 4 + r;
        int el = e - m0;
        int hc = h * C_ + e;
        float bt = p.b_t[hc], mm = p.bn_m[hc], bb = p.bn_b[hc];
        float sc = p.bn_g[hc] / sqrtf(p.bn_v[hc] + BN_EPS);
#pragma unroll
        for (int n = 0; n < 4; ++n) {
          int cl = wc * 64 + n * 16 + l15;
          float y = (acc[m][n][r] + bt - mm) * sc + bb;
          float val = xb[(size_t)e * N_ + n0 + cl] + fmaxf(y, 0.f);
          Tr[cl * 128 + el] = (short)f2b(val);
        }
      }
    __syncthreads();
    short* Hz = p.HOT + (size_t)b * N_ * HC_;
#pragma unroll
    for (int it = 0; it < 8; ++it) {
      int idx = it * 256 + t;
      int cl = idx >> 4, eg = (idx & 15) * 8;
      *(s8v*)(Hz + (size_t)(n0 + cl) * HC_ + h * C_ + m0 + eg) = *(const s8v*)&Tr[cl * 128 + eg];
    }
  } else {
    float* ob = p.out + (size_t)b * C_ * N_;
#pragma unroll
    for (int m = 0; m < 4; ++m)
#pragma unroll
      for (int r = 0; r < 4; ++r) {
        int e = m0 + wr * 64 + m * 16 + l4 * 4 + r;
        float mm = p.lbn_m[e], bb = p.lbn_b[e];
        float sc = p.lbn_g[e] / sqrtf(p.lbn_v[e] + BN_EPS);
#pragma unroll
        for (int n = 0; n < 4; ++n) {
          int c = n0 + wc * 64 + n * 16 + l15;
          float y = (acc[m][n][r] - mm) * sc + bb;
          ob[(size_t)e * N_ + c] = y >= 0.f ? y : 0.2f * y;
        }
      }
  }
}

static inline int imin(int a, int b) { return a < b ? a : b; }

extern "C" void kernel_launch(void* const* d_in, const int* in_sizes, int n_in,
                              void* d_out, int out_size, void* d_ws, size_t ws_size,
                              hipStream_t stream) {
  GP p;
  p.x     = (const float*)d_in[0];
  p.w_qk  = (const float*)d_in[1];
  p.w_v   = (const float*)d_in[2];
  p.b_v   = (const float*)d_in[3];
  p.w_t   = (const float*)d_in[4];
  p.b_t   = (const float*)d_in[5];
  p.bn_g  = (const float*)d_in[6];
  p.bn_b  = (const float*)d_in[7];
  p.bn_m  = (const float*)d_in[8];
  p.bn_v  = (const float*)d_in[9];
  p.w_lin = (const float*)d_in[10];
  p.lbn_g = (const float*)d_in[11];
  p.lbn_b = (const float*)d_in[12];
  p.lbn_m = (const float*)d_in[13];
  p.lbn_v = (const float*)d_in[14];
  p.out   = (float*)d_out;

  char* base = (char*)d_ws;
  size_t off = 0;
  auto alloc = [&](size_t bytes) -> char* {
    char* r = base + off;
    off += (bytes + 255) & ~(size_t)255;
    return r;
  };
  p.PThi  = (short*)alloc((size_t)BH_ * N_ * D_ * 2);
  p.PTlo  = (short*)alloc((size_t)BH_ * N_ * D_ * 2);
  p.xTb   = (short*)alloc((size_t)B_ * N_ * C_ * 2);
  p.HOT   = (short*)alloc((size_t)B_ * N_ * HC_ * 2);
  p.wvb   = (short*)alloc((size_t)H_ * C_ * C_ * 2);
  p.wtb   = (short*)alloc((size_t)H_ * C_ * C_ * 2);
  p.wlinb = (short*)alloc((size_t)C_ * HC_ * 2);
  size_t fixedEnd = off;

  const size_t perz = (size_t)N_ * N_ * 4 + (size_t)N_ * N_ * 2 +
                      (size_t)C_ * N_ * 2 * 2 + 3 * (size_t)N_ * 4 + 4096;
  size_t avail = (ws_size > fixedEnd) ? ws_size - fixedEnd : 0;
  int chunk = (int)(avail / perz);
  if (chunk < 1) chunk = 1;
  if (chunk > BH_) chunk = BH_;

  size_t o2 = fixedEnd;
  p.E   = (float*)(base + o2); o2 += (size_t)chunk * N_ * N_ * 4;
  p.ATT = (short*)(base + o2); o2 += (size_t)chunk * N_ * N_ * 2;
  p.Vb  = (short*)(base + o2); o2 += (size_t)chunk * C_ * N_ * 2;
  p.xmr = (short*)(base + o2); o2 += (size_t)chunk * N_ * C_ * 2;
  p.cs  = (float*)(base + o2); o2 += (size_t)chunk * N_ * 4;
  p.rm  = (float*)(base + o2); o2 += (size_t)chunk * N_ * 4;
  p.rs  = (float*)(base + o2); o2 += (size_t)chunk * N_ * 4;

  dim3 blk(256);
  p.cs0 = 0;

  cvt_k<<<512, blk, 0, stream>>>(p.w_v, p.wvb);
  cvt_k<<<512, blk, 0, stream>>>(p.w_t, p.wtb);
  cvt_k<<<512, blk, 0, stream>>>(p.w_lin, p.wlinb);
  xT_k<<<dim3(32, 4, B_), blk, 0, stream>>>(p.x, p.xTb);
  p_k<<<dim3(32, 1, BH_), blk, 0, stream>>>(p);

  for (int c0 = 0; c0 < BH_; c0 += chunk) {
    int cur = imin(chunk, BH_ - c0);
    p.cs0 = c0;
    mm_k<1><<<dim3(16, 2, cur), blk, 0, stream>>>(p);
    eng_k<<<dim3(16, 16, cur), blk, 0, stream>>>(p);
    sm_pass1<<<dim3(N_, cur), blk, 0, stream>>>(p.E, p.rm, p.rs);
    sm_pass2<<<dim3(N_, cur), blk, 0, stream>>>(p);
    mm_k<2><<<dim3(16, 2, cur), blk, 0, stream>>>(p);
    mm_k<3><<<dim3(16, 2, cur), blk, 0, stream>>>(p);
  }

  p.cs0 = 0;
  mm_k<4><<<dim3(16, 2, B_), blk, 0, stream>>>(p);
}

// Round 3
// 365.498 us; speedup vs baseline: 5.1361x; 2.0559x over previous
//
#include <hip/hip_runtime.h>
#include <math.h>

#define B_ 4
#define C_ 256
#define N_ 2048
#define H_ 8
#define D_ 64
#define BH_ 32
#define HC_ 2048
#define BN_EPS 1e-5f

typedef __attribute__((ext_vector_type(8))) short s8v;
typedef __attribute__((ext_vector_type(4))) short s4v;
typedef __attribute__((ext_vector_type(4))) float f32x4;

#define MFMA __builtin_amdgcn_mfma_f32_16x16x32_bf16

static __device__ __forceinline__ unsigned short f2b(float f) {
  union { float f; unsigned int i; } v; v.f = f;
  unsigned int r = v.i + 0x7FFFu + ((v.i >> 16) & 1u);
  return (unsigned short)(r >> 16);
}
static __device__ __forceinline__ float b2f(unsigned short u) {
  union { unsigned int i; float f; } v; v.i = ((unsigned int)u) << 16;
  return v.f;
}

struct GP {
  const float *x, *w_qk, *w_v, *b_v, *w_t, *b_t, *bn_g, *bn_b, *bn_m, *bn_v;
  const float *w_lin, *lbn_g, *lbn_b, *lbn_m, *lbn_v;
  short *PThi, *PTlo, *xThi, *xTlo, *HOT, *wvb, *wtb, *wlinb, *wqkh, *wqkl, *Vb, *xmr;
  float *rm, *rs, *out;
};

// fp32 -> bf16 (524288 elems)
__global__ __launch_bounds__(256) void cvt_k(const float* __restrict__ in,
                                             short* __restrict__ out) {
  int i = (blockIdx.x * 256 + threadIdx.x) * 4;
  float4 v = *(const float4*)(in + i);
  s4v o = { (short)f2b(v.x), (short)f2b(v.y), (short)f2b(v.z), (short)f2b(v.w) };
  *(s4v*)(out + i) = o;
}

// fp32 -> bf16 hi/lo split (131072 elems)
__global__ __launch_bounds__(256) void cvtqk_k(const float* __restrict__ in,
                                               short* __restrict__ oh,
                                               short* __restrict__ ol) {
  int i = (blockIdx.x * 256 + threadIdx.x) * 4;
  float4 v = *(const float4*)(in + i);
  float a[4] = {v.x, v.y, v.z, v.w};
  s4v h, l;
#pragma unroll
  for (int e = 0; e < 4; ++e) {
    unsigned short hu = f2b(a[e]);
    h[e] = (short)hu;
    l[e] = (short)f2b(a[e] - b2f(hu));
  }
  *(s4v*)(oh + i) = h;
  *(s4v*)(ol + i) = l;
}

// x [B][C][N] fp32 -> xThi/xTlo [B][N][C] bf16 hi/lo
__global__ __launch_bounds__(256) void xsplit_k(const float* __restrict__ x,
                                                short* __restrict__ xh,
                                                short* __restrict__ xl) {
  const int n0 = blockIdx.x * 64, c0 = blockIdx.y * 64, b = blockIdx.z;
  const float* xb = x + (size_t)b * C_ * N_;
  __shared__ float sm[64][65];
  const int t = threadIdx.x;
#pragma unroll
  for (int i = 0; i < 4; ++i) {
    int idx = i * 256 + t;
    int c = idx >> 4, j = (idx & 15) * 4;
    float4 v = *(const float4*)(xb + (size_t)(c0 + c) * N_ + n0 + j);
    sm[j + 0][c] = v.x; sm[j + 1][c] = v.y; sm[j + 2][c] = v.z; sm[j + 3][c] = v.w;
  }
  __syncthreads();
#pragma unroll
  for (int i = 0; i < 2; ++i) {
    int idx = i * 256 + t;
    int n = idx >> 3, cg = (idx & 7) * 8;
    s8v hh, ll;
#pragma unroll
    for (int d = 0; d < 8; ++d) {
      float v = sm[n][cg + d];
      unsigned short hu = f2b(v);
      hh[d] = (short)hu;
      ll[d] = (short)f2b(v - b2f(hu));
    }
    size_t o = ((size_t)b * N_ + n0 + n) * C_ + c0 + cg;
    *(s8v*)(xh + o) = hh;
    *(s8v*)(xl + o) = ll;
  }
}

// P = w_qk*x via hi/lo MFMA (fp32-accurate); writes PThi/PTlo [bh][N][D]
__global__ __launch_bounds__(256, 2) void p_k(GP p) {
  const int t = threadIdx.x, wv = t >> 6, lane = t & 63;
  const int l15 = lane & 15, l4 = lane >> 4;
  const int n0 = blockIdx.x * 128;
  const int bh = blockIdx.y, b = bh / H_, h = bh % H_;
  const short* Ah_g = p.wqkh + h * D_ * C_;
  const short* Al_g = p.wqkl + h * D_ * C_;
  const short* Bh_g = p.xThi + (size_t)b * N_ * C_;
  const short* Bl_g = p.xTlo + (size_t)b * N_ * C_;
  __shared__ short AsH[64 * 64], AsL[64 * 64], BsH[128 * 64], BsL[128 * 64];
  __shared__ float Tr[128 * 65];
  f32x4 acc[4][2] = {};
  for (int kc = 0; kc < 256; kc += 64) {
    __syncthreads();
#pragma unroll
    for (int i = 0; i < 2; ++i) {
      int idx = i * 256 + t;
      int row = idx >> 3, off = (idx & 7) * 16;
      int dst = row * 128 + (off ^ ((row & 7) << 4));
      *(s8v*)((char*)AsH + dst) = *(const s8v*)((const char*)(Ah_g + (size_t)row * C_ + kc) + off);
      *(s8v*)((char*)AsL + dst) = *(const s8v*)((const char*)(Al_g + (size_t)row * C_ + kc) + off);
    }
#pragma unroll
    for (int i = 0; i < 4; ++i) {
      int idx = i * 256 + t;
      int row = idx >> 3, off = (idx & 7) * 16;
      int dst = row * 128 + (off ^ ((row & 7) << 4));
      *(s8v*)((char*)BsH + dst) = *(const s8v*)((const char*)(Bh_g + (size_t)(n0 + row) * C_ + kc) + off);
      *(s8v*)((char*)BsL + dst) = *(const s8v*)((const char*)(Bl_g + (size_t)(n0 + row) * C_ + kc) + off);
    }
    __syncthreads();
    s8v adh[4][2], adl[4][2], bnh[2][2], bnl[2][2];
#pragma unroll
    for (int d = 0; d < 4; ++d)
#pragma unroll
      for (int ks = 0; ks < 2; ++ks) {
        int row = d * 16 + l15;
        int byte = row * 128 + ((ks * 64 + l4 * 16) ^ ((row & 7) << 4));
        adh[d][ks] = *(const s8v*)((const char*)AsH + byte);
        adl[d][ks] = *(const s8v*)((const char*)AsL + byte);
      }
#pragma unroll
    for (int nb = 0; nb < 2; ++nb)
#pragma unroll
      for (int ks = 0; ks < 2; ++ks) {
        int row = wv * 32 + nb * 16 + l15;
        int byte = row * 128 + ((ks * 64 + l4 * 16) ^ ((row & 7) << 4));
        bnh[nb][ks] = *(const s8v*)((const char*)BsH + byte);
        bnl[nb][ks] = *(const s8v*)((const char*)BsL + byte);
      }
#pragma unroll
    for (int d = 0; d < 4; ++d)
#pragma unroll
      for (int nb = 0; nb < 2; ++nb) {
        acc[d][nb] = MFMA(adh[d][0], bnh[nb][0], acc[d][nb], 0, 0, 0);
        acc[d][nb] = MFMA(adh[d][1], bnh[nb][1], acc[d][nb], 0, 0, 0);
        acc[d][nb] = MFMA(adh[d][0], bnl[nb][0], acc[d][nb], 0, 0, 0);
        acc[d][nb] = MFMA(adh[d][1], bnl[nb][1], acc[d][nb], 0, 0, 0);
        acc[d][nb] = MFMA(adl[d][0], bnh[nb][0], acc[d][nb], 0, 0, 0);
        acc[d][nb] = MFMA(adl[d][1], bnh[nb][1], acc[d][nb], 0, 0, 0);
      }
  }
  __syncthreads();
#pragma unroll
  for (int d = 0; d < 4; ++d)
#pragma unroll
    for (int nb = 0; nb < 2; ++nb)
#pragma unroll
      for (int r = 0; r < 4; ++r) {
        int n_l = wv * 32 + nb * 16 + l15;
        int dd = d * 16 + l4 * 4 + r;
        Tr[n_l * 65 + dd] = acc[d][nb][r];
      }
  __syncthreads();
  short* Ph = p.PThi + ((size_t)bh * N_ + n0) * D_;
  short* Pl = p.PTlo + ((size_t)bh * N_ + n0) * D_;
#pragma unroll
  for (int i = 0; i < 4; ++i) {
    int idx = i * 256 + t;
    int n = idx >> 3, dg = (idx & 7) * 8;
    s8v hh, ll;
#pragma unroll
    for (int j = 0; j < 8; ++j) {
      float v = Tr[n * 65 + dg + j];
      unsigned short hu = f2b(v);
      hh[j] = (short)hu;
      ll[j] = (short)f2b(v - b2f(hu));
    }
    *(s8v*)(Ph + (size_t)n * D_ + dg) = hh;
    *(s8v*)(Pl + (size_t)n * D_ + dg) = ll;
  }
}

// pass A: rm/rs via online softmax over recomputed E tiles
__global__ __launch_bounds__(256, 2) void passa_k(GP p) {
  const int t = threadIdx.x, wv = t >> 6, lane = t & 63;
  const int l15 = lane & 15, l4 = lane >> 4;
  const int n0 = blockIdx.x * 64;
  const int z = blockIdx.y;
  const short* Phi = p.PThi + (size_t)z * N_ * D_;
  const short* Plo = p.PTlo + (size_t)z * N_ * D_;
  __shared__ short PnH[4096], PnL[4096], PmH[4096], PmL[4096];
  __shared__ float red[2][4][4][16];
#pragma unroll
  for (int i = 0; i < 2; ++i) {
    int idx = i * 256 + t;
    int row = idx >> 3, off = (idx & 7) * 16;
    int dst = row * 128 + (off ^ ((row & 7) << 4));
    *(s8v*)((char*)PnH + dst) = *(const s8v*)((const char*)(Phi + (size_t)(n0 + row) * D_) + off);
    *(s8v*)((char*)PnL + dst) = *(const s8v*)((const char*)(Plo + (size_t)(n0 + row) * D_) + off);
  }
  __syncthreads();
  s8v bnh[4][2], bnl[4][2];
#pragma unroll
  for (int nb = 0; nb < 4; ++nb)
#pragma unroll
    for (int ks = 0; ks < 2; ++ks) {
      int row = nb * 16 + l15;
      int byte = row * 128 + ((ks * 64 + l4 * 16) ^ ((row & 7) << 4));
      bnh[nb][ks] = *(const s8v*)((const char*)PnH + byte);
      bnl[nb][ks] = *(const s8v*)((const char*)PnL + byte);
    }
  float Mx[4] = {-INFINITY, -INFINITY, -INFINITY, -INFINITY};
  float Sm[4] = {0.f, 0.f, 0.f, 0.f};
  for (int m0 = 0; m0 < N_; m0 += 64) {
    __syncthreads();
#pragma unroll
    for (int i = 0; i < 2; ++i) {
      int idx = i * 256 + t;
      int row = idx >> 3, off = (idx & 7) * 16;
      int dst = row * 128 + (off ^ ((row & 7) << 4));
      *(s8v*)((char*)PmH + dst) = *(const s8v*)((const char*)(Phi + (size_t)(m0 + row) * D_) + off);
      *(s8v*)((char*)PmL + dst) = *(const s8v*)((const char*)(Plo + (size_t)(m0 + row) * D_) + off);
    }
    __syncthreads();
    s8v amh[2], aml[2];
#pragma unroll
    for (int ks = 0; ks < 2; ++ks) {
      int row = wv * 16 + l15;
      int byte = row * 128 + ((ks * 64 + l4 * 16) ^ ((row & 7) << 4));
      amh[ks] = *(const s8v*)((const char*)PmH + byte);
      aml[ks] = *(const s8v*)((const char*)PmL + byte);
    }
#pragma unroll
    for (int nb = 0; nb < 4; ++nb) {
      f32x4 s = {};
      s = MFMA(amh[0], bnh[nb][0], s, 0, 0, 0);
      s = MFMA(amh[1], bnh[nb][1], s, 0, 0, 0);
      s = MFMA(amh[0], bnl[nb][0], s, 0, 0, 0);
      s = MFMA(amh[1], bnl[nb][1], s, 0, 0, 0);
      s = MFMA(aml[0], bnh[nb][0], s, 0, 0, 0);
      s = MFMA(aml[1], bnh[nb][1], s, 0, 0, 0);
      float tm = fmaxf(fmaxf(s[0], s[1]), fmaxf(s[2], s[3]));
      float nm = fmaxf(Mx[nb], tm);
      Sm[nb] = Sm[nb] * __expf(Mx[nb] - nm) + __expf(s[0] - nm) + __expf(s[1] - nm) +
               __expf(s[2] - nm) + __expf(s[3] - nm);
      Mx[nb] = nm;
    }
  }
#pragma unroll
  for (int nb = 0; nb < 4; ++nb) {
#pragma unroll
    for (int o = 16; o <= 32; o <<= 1) {
      float mo = __shfl_xor(Mx[nb], o, 64);
      float so = __shfl_xor(Sm[nb], o, 64);
      float nm = fmaxf(Mx[nb], mo);
      Sm[nb] = Sm[nb] * __expf(Mx[nb] - nm) + so * __expf(mo - nm);
      Mx[nb] = nm;
    }
    if (l4 == 0) {
      red[0][wv][nb][l15] = Mx[nb];
      red[1][wv][nb][l15] = Sm[nb];
    }
  }
  __syncthreads();
  if (t < 64) {
    int nb = t >> 4, i15 = t & 15;
    float M = -INFINITY, S = 0.f;
#pragma unroll
    for (int w = 0; w < 4; ++w) {
      float m2 = red[0][w][nb][i15], s2 = red[1][w][nb][i15];
      float nm = fmaxf(M, m2);
      S = S * __expf(M - nm) + s2 * __expf(m2 - nm);
      M = nm;
    }
    p.rm[(size_t)z * N_ + n0 + t] = M;
    p.rs[(size_t)z * N_ + n0 + t] = 1.0f / S;
  }
}

// pass B: fused exp + PV + colsum renorm; writes xmr = (x - x_r)^T bf16
__global__ __launch_bounds__(256, 2) void passb_k(GP p) {
  const int t = threadIdx.x, wv = t >> 6, lane = t & 63;
  const int l15 = lane & 15, l4 = lane >> 4;
  const int m0 = blockIdx.x * 64;
  const int z = blockIdx.y, b = z / H_;
  const short* Phi = p.PThi + (size_t)z * N_ * D_;
  const short* Plo = p.PTlo + (size_t)z * N_ * D_;
  const short* Vz = p.Vb + (size_t)z * C_ * N_;
  const float* rmz = p.rm + (size_t)z * N_;
  const float* rsz = p.rs + (size_t)z * N_;
  __shared__ short PmH[4096], PmL[4096], PnH[4096], PnL[4096];
  __shared__ short Vs[256 * 64];
  __shared__ short ATs[4096];
  __shared__ float cs_sm[64];
#pragma unroll
  for (int i = 0; i < 2; ++i) {
    int idx = i * 256 + t;
    int row = idx >> 3, off = (idx & 7) * 16;
    int dst = row * 128 + (off ^ ((row & 7) << 4));
    *(s8v*)((char*)PmH + dst) = *(const s8v*)((const char*)(Phi + (size_t)(m0 + row) * D_) + off);
    *(s8v*)((char*)PmL + dst) = *(const s8v*)((const char*)(Plo + (size_t)(m0 + row) * D_) + off);
  }
  __syncthreads();
  s8v bmh[2], bml[2];
  const int mrow = wv * 16 + l15;
#pragma unroll
  for (int ks = 0; ks < 2; ++ks) {
    int byte = mrow * 128 + ((ks * 64 + l4 * 16) ^ ((mrow & 7) << 4));
    bmh[ks] = *(const s8v*)((const char*)PmH + byte);
    bml[ks] = *(const s8v*)((const char*)PmL + byte);
  }
  f32x4 racc[4][4] = {};
  float csacc = 0.f;
  for (int n0 = 0; n0 < N_; n0 += 64) {
    __syncthreads();
#pragma unroll
    for (int i = 0; i < 2; ++i) {
      int idx = i * 256 + t;
      int row = idx >> 3, off = (idx & 7) * 16;
      int dst = row * 128 + (off ^ ((row & 7) << 4));
      *(s8v*)((char*)PnH + dst) = *(const s8v*)((const char*)(Phi + (size_t)(n0 + row) * D_) + off);
      *(s8v*)((char*)PnL + dst) = *(const s8v*)((const char*)(Plo + (size_t)(n0 + row) * D_) + off);
    }
#pragma unroll
    for (int i = 0; i < 8; ++i) {
      int idx = i * 256 + t;
      int e = idx >> 3, off = (idx & 7) * 16;
      int dst = e * 128 + (off ^ ((e & 7) << 4));
      *(s8v*)((char*)Vs + dst) = *(const s8v*)((const char*)(Vz + (size_t)e * N_ + n0) + off);
    }
    __syncthreads();
#pragma unroll
    for (int nb = 0; nb < 4; ++nb) {
      s8v anh[2], anl[2];
#pragma unroll
      for (int ks = 0; ks < 2; ++ks) {
        int row = nb * 16 + l15;
        int byte = row * 128 + ((ks * 64 + l4 * 16) ^ ((row & 7) << 4));
        anh[ks] = *(const s8v*)((const char*)PnH + byte);
        anl[ks] = *(const s8v*)((const char*)PnL + byte);
      }
      f32x4 s = {};
      s = MFMA(anh[0], bmh[0], s, 0, 0, 0);
      s = MFMA(anh[1], bmh[1], s, 0, 0, 0);
      s = MFMA(anh[0], bml[0], s, 0, 0, 0);
      s = MFMA(anh[1], bml[1], s, 0, 0, 0);
      s = MFMA(anl[0], bmh[0], s, 0, 0, 0);
      s = MFMA(anl[1], bmh[1], s, 0, 0, 0);
      f32x4 rm4 = *(const f32x4*)(rmz + n0 + nb * 16 + l4 * 4);
      f32x4 rs4 = *(const f32x4*)(rsz + n0 + nb * 16 + l4 * 4);
      float a0 = __expf(s[0] - rm4[0]) * rs4[0];
      float a1 = __expf(s[1] - rm4[1]) * rs4[1];
      float a2 = __expf(s[2] - rm4[2]) * rs4[2];
      float a3 = __expf(s[3] - rm4[3]) * rs4[3];
      csacc += a0 + a1 + a2 + a3;
      s4v pk = { (short)f2b(a0), (short)f2b(a1), (short)f2b(a2), (short)f2b(a3) };
      int wbyte = mrow * 128 + ((nb * 32 + l4 * 8) ^ ((mrow & 7) << 4));
      *(s4v*)((char*)ATs + wbyte) = pk;
    }
    __syncthreads();
    s8v at[4][2];
#pragma unroll
    for (int mb = 0; mb < 4; ++mb)
#pragma unroll
      for (int ks = 0; ks < 2; ++ks) {
        int row = mb * 16 + l15;
        int byte = row * 128 + ((ks * 64 + l4 * 16) ^ ((row & 7) << 4));
        at[mb][ks] = *(const s8v*)((const char*)ATs + byte);
      }
#pragma unroll
    for (int eb = 0; eb < 4; ++eb) {
      s8v va[2];
#pragma unroll
      for (int ks = 0; ks < 2; ++ks) {
        int erow = wv * 64 + eb * 16 + l15;
        int byte = erow * 128 + ((ks * 64 + l4 * 16) ^ ((erow & 7) << 4));
        va[ks] = *(const s8v*)((const char*)Vs + byte);
      }
#pragma unroll
      for (int mb = 0; mb < 4; ++mb) {
        racc[eb][mb] = MFMA(va[0], at[mb][0], racc[eb][mb], 0, 0, 0);
        racc[eb][mb] = MFMA(va[1], at[mb][1], racc[eb][mb], 0, 0, 0);
      }
    }
  }
  csacc += __shfl_xor(csacc, 16, 64);
  csacc += __shfl_xor(csacc, 32, 64);
  if (l4 == 0) cs_sm[mrow] = csacc;
  __syncthreads();
  float invc[4];
#pragma unroll
  for (int mb = 0; mb < 4; ++mb) invc[mb] = 1.0f / (1e-9f + cs_sm[mb * 16 + l15]);
  const float* xb = p.x + (size_t)b * C_ * N_;
  short* Tr = Vs;
#pragma unroll
  for (int eb = 0; eb < 4; ++eb)
#pragma unroll
    for (int mb = 0; mb < 4; ++mb)
#pragma unroll
      for (int r = 0; r < 4; ++r) {
        int e = wv * 64 + eb * 16 + l4 * 4 + r;
        int mg = m0 + mb * 16 + l15;
        float val = xb[(size_t)e * N_ + mg] - racc[eb][mb][r] * invc[mb];
        int m_l = mb * 16 + l15;
        int byte = m_l * 512 + ((e * 2) ^ ((m_l & 7) << 4));
        *(short*)((char*)Tr + byte) = (short)f2b(val);
      }
  __syncthreads();
  short* xz = p.xmr + ((size_t)z * N_ + m0) * C_;
#pragma unroll
  for (int i = 0; i < 8; ++i) {
    int idx = i * 256 + t;
    int m_l = idx >> 5, off = (idx & 31) * 16;
    s8v v = *(const s8v*)((char*)Tr + m_l * 512 + (off ^ ((m_l & 7) << 4)));
    *(s8v*)((char*)(xz + (size_t)m_l * C_) + off) = v;
  }
}

// bf16 MFMA GEMM, 128x128 tile.
// EPI 1: V = w_v*x + b_v -> Vb [z][C][N]
// EPI 3: HO = x + relu(bn(w_t*xmr^T + b_t)) -> HOT [b][N][HC]
// EPI 4: out = leaky(bn(w_lin*HOT^T)) fp32 [b][C][N]
template<int EPI>
__global__ __launch_bounds__(256) void mm_k(GP p) {
  constexpr int K = (EPI == 4) ? 2048 : 256;
  const int t = threadIdx.x;
  const int wave = t >> 6, lane = t & 63;
  const int wr = wave >> 1, wc = wave & 1;
  const int l15 = lane & 15, l4 = lane >> 4;
  const int n0 = blockIdx.x * 128;
  const int m0 = blockIdx.y * 128;
  const int z = blockIdx.z;
  int bh = z, b = bh / H_, h = bh % H_;

  const short *Ag, *Bg;
  if constexpr (EPI == 1)      { Ag = p.wvb + h * C_ * C_; Bg = p.xThi + (size_t)b * N_ * C_; }
  else if constexpr (EPI == 3) { Ag = p.wtb + h * C_ * C_; Bg = p.xmr + (size_t)z * N_ * C_; }
  else                         { Ag = p.wlinb; Bg = p.HOT + (size_t)z * N_ * HC_; b = z; }

  __shared__ short As[128 * 32];
  __shared__ short Bs[128 * 32];

  f32x4 acc[4][4] = {};

  for (int k0 = 0; k0 < K; k0 += 32) {
    s8v va[2], vb[2];
#pragma unroll
    for (int i = 0; i < 2; ++i) {
      int idx = i * 256 + t;
      int row = idx >> 2, kg = (idx & 3) * 8;
      va[i] = *(const s8v*)(Ag + (size_t)(m0 + row) * K + k0 + kg);
      vb[i] = *(const s8v*)(Bg + (size_t)(n0 + row) * K + k0 + kg);
    }
    __syncthreads();
#pragma unroll
    for (int i = 0; i < 2; ++i) {
      int idx = i * 256 + t;
      int row = idx >> 2, kg = (idx & 3) * 8;
      *(s8v*)&As[row * 32 + kg] = va[i];
      *(s8v*)&Bs[row * 32 + kg] = vb[i];
    }
    __syncthreads();
    s8v af[4], bf[4];
#pragma unroll
    for (int m = 0; m < 4; ++m) af[m] = *(const s8v*)&As[(wr * 64 + m * 16 + l15) * 32 + l4 * 8];
#pragma unroll
    for (int n = 0; n < 4; ++n) bf[n] = *(const s8v*)&Bs[(wc * 64 + n * 16 + l15) * 32 + l4 * 8];
#pragma unroll
    for (int m = 0; m < 4; ++m)
#pragma unroll
      for (int n = 0; n < 4; ++n)
        acc[m][n] = MFMA(af[m], bf[n], acc[m][n], 0, 0, 0);
  }

  if constexpr (EPI == 1) {
    short* Vz = p.Vb + (size_t)z * C_ * N_;
#pragma unroll
    for (int m = 0; m < 4; ++m)
#pragma unroll
      for (int r = 0; r < 4; ++r) {
        int e = m0 + wr * 64 + m * 16 + l4 * 4 + r;
        float bias = p.b_v[h * C_ + e];
#pragma unroll
        for (int n = 0; n < 4; ++n) {
          int c = n0 + wc * 64 + n * 16 + l15;
          Vz[(size_t)e * N_ + c] = (short)f2b(acc[m][n][r] + bias);
        }
      }
  } else if constexpr (EPI == 3) {
    __shared__ short Tr[128 * 128];
    const float* xb = p.x + (size_t)b * C_ * N_;
#pragma unroll
    for (int m = 0; m < 4; ++m)
#pragma unroll
      for (int r = 0; r < 4; ++r) {
        int e = m0 + wr * 64 + m * 16 + l4 * 4 + r;
        int el = e - m0;
        int hc = h * C_ + e;
        float bt = p.b_t[hc], mm = p.bn_m[hc], bb = p.bn_b[hc];
        float sc = p.bn_g[hc] / sqrtf(p.bn_v[hc] + BN_EPS);
#pragma unroll
        for (int n = 0; n < 4; ++n) {
          int cl = wc * 64 + n * 16 + l15;
          float y = (acc[m][n][r] + bt - mm) * sc + bb;
          float val = xb[(size_t)e * N_ + n0 + cl] + fmaxf(y, 0.f);
          Tr[cl * 128 + el] = (short)f2b(val);
        }
      }
    __syncthreads();
    short* Hz = p.HOT + (size_t)b * N_ * HC_;
#pragma unroll
    for (int it = 0; it < 8; ++it) {
      int idx = it * 256 + t;
      int cl = idx >> 4, eg = (idx & 15) * 8;
      *(s8v*)(Hz + (size_t)(n0 + cl) * HC_ + h * C_ + m0 + eg) = *(const s8v*)&Tr[cl * 128 + eg];
    }
  } else {
    float* ob = p.out + (size_t)b * C_ * N_;
#pragma unroll
    for (int m = 0; m < 4; ++m)
#pragma unroll
      for (int r = 0; r < 4; ++r) {
        int e = m0 + wr * 64 + m * 16 + l4 * 4 + r;
        float mm = p.lbn_m[e], bb = p.lbn_b[e];
        float sc = p.lbn_g[e] / sqrtf(p.lbn_v[e] + BN_EPS);
#pragma unroll
        for (int n = 0; n < 4; ++n) {
          int c = n0 + wc * 64 + n * 16 + l15;
          float y = (acc[m][n][r] - mm) * sc + bb;
          ob[(size_t)e * N_ + c] = y >= 0.f ? y : 0.2f * y;
        }
      }
  }
}

extern "C" void kernel_launch(void* const* d_in, const int* in_sizes, int n_in,
                              void* d_out, int out_size, void* d_ws, size_t ws_size,
                              hipStream_t stream) {
  GP p;
  p.x     = (const float*)d_in[0];
  p.w_qk  = (const float*)d_in[1];
  p.w_v   = (const float*)d_in[2];
  p.b_v   = (const float*)d_in[3];
  p.w_t   = (const float*)d_in[4];
  p.b_t   = (const float*)d_in[5];
  p.bn_g  = (const float*)d_in[6];
  p.bn_b  = (const float*)d_in[7];
  p.bn_m  = (const float*)d_in[8];
  p.bn_v  = (const float*)d_in[9];
  p.w_lin = (const float*)d_in[10];
  p.lbn_g = (const float*)d_in[11];
  p.lbn_b = (const float*)d_in[12];
  p.lbn_m = (const float*)d_in[13];
  p.lbn_v = (const float*)d_in[14];
  p.out   = (float*)d_out;

  char* base = (char*)d_ws;
  size_t off = 0;
  auto alloc = [&](size_t bytes) -> char* {
    char* r = base + off;
    off += (bytes + 255) & ~(size_t)255;
    return r;
  };
  p.PThi  = (short*)alloc((size_t)BH_ * N_ * D_ * 2);
  p.PTlo  = (short*)alloc((size_t)BH_ * N_ * D_ * 2);
  p.xThi  = (short*)alloc((size_t)B_ * N_ * C_ * 2);
  p.xTlo  = (short*)alloc((size_t)B_ * N_ * C_ * 2);
  p.wqkh  = (short*)alloc((size_t)H_ * D_ * C_ * 2);
  p.wqkl  = (short*)alloc((size_t)H_ * D_ * C_ * 2);
  p.wvb   = (short*)alloc((size_t)H_ * C_ * C_ * 2);
  p.wtb   = (short*)alloc((size_t)H_ * C_ * C_ * 2);
  p.wlinb = (short*)alloc((size_t)C_ * HC_ * 2);
  p.Vb    = (short*)alloc((size_t)BH_ * C_ * N_ * 2);
  p.xmr   = (short*)alloc((size_t)BH_ * N_ * C_ * 2);
  p.rm    = (float*)alloc((size_t)BH_ * N_ * 4);
  p.rs    = (float*)alloc((size_t)BH_ * N_ * 4);
  p.HOT   = p.Vb;  // alias: Vb dead after passb_k, HOT same size (32 MB)

  dim3 blk(256);

  cvt_k<<<512, blk, 0, stream>>>(p.w_v, p.wvb);
  cvt_k<<<512, blk, 0, stream>>>(p.w_t, p.wtb);
  cvt_k<<<512, blk, 0, stream>>>(p.w_lin, p.wlinb);
  cvtqk_k<<<128, blk, 0, stream>>>(p.w_qk, p.wqkh, p.wqkl);
  xsplit_k<<<dim3(32, 4, B_), blk, 0, stream>>>(p.x, p.xThi, p.xTlo);
  p_k<<<dim3(16, BH_), blk, 0, stream>>>(p);
  mm_k<1><<<dim3(16, 2, BH_), blk, 0, stream>>>(p);
  passa_k<<<dim3(32, BH_), blk, 0, stream>>>(p);
  passb_k<<<dim3(32, BH_), blk, 0, stream>>>(p);
  mm_k<3><<<dim3(16, 2, BH_), blk, 0, stream>>>(p);
  mm_k<4><<<dim3(16, 2, B_), blk, 0, stream>>>(p);
}